// Round 15
// baseline (693.165 us; speedup 1.0000x reference)
//
#include <hip/hip_runtime.h>
#include <hip/hip_bf16.h>

#define ND 20000
#define NP 8000
#define NE 640000
#define NL 200000
#define DD 128
#define HH 256

typedef __attribute__((ext_vector_type(8))) short short8;
typedef __attribute__((ext_vector_type(4))) float f32x4;

__device__ inline float bflo(unsigned int u) {
    union { unsigned int u; float f; } x; x.u = u << 16; return x.f;
}
__device__ inline float bfhi(unsigned int u) {
    union { unsigned int u; float f; } x; x.u = u & 0xffff0000u; return x.f;
}
__device__ inline unsigned short f2b(float f) {  // RNE f32->bf16
    union { float f; unsigned int u; } x; x.f = f;
    unsigned int r = x.u + 0x7fffu + ((x.u >> 16) & 1u);
    return (unsigned short)(r >> 16);
}

// ---------------- CSR build ----------------
__global__ void k_hist(const int* __restrict__ src, const int* __restrict__ dst,
                       int* __restrict__ deg_d, int* __restrict__ deg_p) {
    int i = blockIdx.x * blockDim.x + threadIdx.x;
    if (i < NE) {
        atomicAdd(&deg_p[dst[i]], 1);
        atomicAdd(&deg_d[src[i]], 1);
    }
}

// merged dual scan: block 0 -> (degA,...), block 1 -> (degB,...)
__global__ void k_scan2(const int* __restrict__ degA, int* __restrict__ rowA,
                        int* __restrict__ curA, int nA,
                        const int* __restrict__ degB, int* __restrict__ rowB,
                        int* __restrict__ curB, int nB) {
    __shared__ int s[1024];
    const int* deg; int* rowptr; int* cursor; int n;
    if (blockIdx.x == 0) { deg = degA; rowptr = rowA; cursor = curA; n = nA; }
    else                 { deg = degB; rowptr = rowB; cursor = curB; n = nB; }
    const int t = threadIdx.x;
    const int chunk = (n + 1023) / 1024;
    const int lo = t * chunk;
    const int hi = min(n, lo + chunk);
    int local = 0;
    for (int i = lo; i < hi; ++i) local += deg[i];
    s[t] = local;
    __syncthreads();
    for (int off = 1; off < 1024; off <<= 1) {
        int v = (t >= off) ? s[t - off] : 0;
        __syncthreads();
        s[t] += v;
        __syncthreads();
    }
    int base = s[t] - local;
    for (int i = lo; i < hi; ++i) {
        rowptr[i] = base;
        cursor[i] = base;
        base += deg[i];
    }
    if (t == 1023) rowptr[n] = s[1023];
}

__global__ void k_fill(const int* __restrict__ src, const int* __restrict__ dst,
                       int* __restrict__ cur_p, int* __restrict__ cur_d,
                       int* __restrict__ csr_p, int* __restrict__ csr_d) {
    int i = blockIdx.x * blockDim.x + threadIdx.x;
    if (i < NE) {
        int s = src[i], d = dst[i];
        csr_p[atomicAdd(&cur_p[d], 1)] = s;
        csr_d[atomicAdd(&cur_d[s], 1)] = d;
    }
}

// ---------------- merged f32 -> bf16 convert (both feature tables) ----------------
__global__ void k_f2b2(const float* __restrict__ a, unsigned short* __restrict__ oa, int n4a,
                       const float* __restrict__ b, unsigned short* __restrict__ ob, int n4b) {
    int i = blockIdx.x * blockDim.x + threadIdx.x;
    if (i < n4a) {
        float4 v = ((const float4*)a)[i];
        ushort4 o; o.x = f2b(v.x); o.y = f2b(v.y); o.z = f2b(v.z); o.w = f2b(v.w);
        ((ushort4*)oa)[i] = o;
    } else if (i - n4a < n4b) {
        int j = i - n4a;
        float4 v = ((const float4*)b)[j];
        ushort4 o; o.x = f2b(v.x); o.y = f2b(v.y); o.z = f2b(v.z); o.w = f2b(v.w);
        ((ushort4*)ob)[j] = o;
    }
}

// ---------------- weight transpose+convert: dst[n][k] = bf16(src[k][n]) ----------------
struct WtD { const float* src; unsigned short* dst; int kbits; };
struct WtPack { WtD d[14]; };
__global__ void k_wt(WtPack p) {
    WtD d = p.d[blockIdx.y];
    const int K = 1 << d.kbits;
    int i = blockIdx.x * blockDim.x + threadIdx.x;
    if (i < 256 * K) {
        int nn = i >> d.kbits, k = i & (K - 1);
        d.dst[i] = f2b(d.src[k * 256 + nn]);
    }
}

// ---------------- merged dual-side bf16 CSR aggregate ----------------
// 256 threads = 4 waves per block, ONE NODE PER WAVE (occupancy: 1-wave blocks cap
// at ~16 wg/CU = 50%; 4-wave blocks reach 32 waves/CU). 4-row unroll for MLP.
struct ASide { const unsigned short* x; const int* rowptr; const int* idx;
               unsigned short* agg; int n; };

__global__ __launch_bounds__(256)
void k_agg2_128(ASide s0, ASide s1) {
    const int w = threadIdx.x >> 6, t = threadIdx.x & 63;
    int ni = blockIdx.x * 4 + w;
    ASide S; int b;
    if (ni < s0.n) { S = s0; b = ni; }
    else { b = ni - s0.n; if (b >= s1.n) return; S = s1; }
    const int s = S.rowptr[b], e = S.rowptr[b + 1];
    float a0 = 0.f, a1 = 0.f;
    int j = s;
    for (; j + 3 < e; j += 4) {
        int r0 = S.idx[j], r1 = S.idx[j + 1], r2 = S.idx[j + 2], r3 = S.idx[j + 3];
        unsigned int u0 = *(const unsigned int*)(S.x + (size_t)r0 * 128 + 2 * t);
        unsigned int u1 = *(const unsigned int*)(S.x + (size_t)r1 * 128 + 2 * t);
        unsigned int u2 = *(const unsigned int*)(S.x + (size_t)r2 * 128 + 2 * t);
        unsigned int u3 = *(const unsigned int*)(S.x + (size_t)r3 * 128 + 2 * t);
        a0 += (bflo(u0) + bflo(u1)) + (bflo(u2) + bflo(u3));
        a1 += (bfhi(u0) + bfhi(u1)) + (bfhi(u2) + bfhi(u3));
    }
    for (; j < e; ++j) {
        unsigned int u = *(const unsigned int*)(S.x + (size_t)S.idx[j] * 128 + 2 * t);
        a0 += bflo(u); a1 += bfhi(u);
    }
    S.agg[(size_t)b * 128 + 2 * t]     = f2b(a0);
    S.agg[(size_t)b * 128 + 2 * t + 1] = f2b(a1);
}

__global__ __launch_bounds__(256)
void k_agg2_256(ASide s0, ASide s1) {
    const int w = threadIdx.x >> 6, t = threadIdx.x & 63;
    int ni = blockIdx.x * 4 + w;
    ASide S; int b;
    if (ni < s0.n) { S = s0; b = ni; }
    else { b = ni - s0.n; if (b >= s1.n) return; S = s1; }
    const int s = S.rowptr[b], e = S.rowptr[b + 1];
    float a0 = 0.f, a1 = 0.f, a2 = 0.f, a3 = 0.f;
    int j = s;
    for (; j + 3 < e; j += 4) {
        int r0 = S.idx[j], r1 = S.idx[j + 1], r2 = S.idx[j + 2], r3 = S.idx[j + 3];
        uint2 u0 = *(const uint2*)(S.x + (size_t)r0 * 256 + 4 * t);
        uint2 u1 = *(const uint2*)(S.x + (size_t)r1 * 256 + 4 * t);
        uint2 u2 = *(const uint2*)(S.x + (size_t)r2 * 256 + 4 * t);
        uint2 u3 = *(const uint2*)(S.x + (size_t)r3 * 256 + 4 * t);
        a0 += (bflo(u0.x) + bflo(u1.x)) + (bflo(u2.x) + bflo(u3.x));
        a1 += (bfhi(u0.x) + bfhi(u1.x)) + (bfhi(u2.x) + bfhi(u3.x));
        a2 += (bflo(u0.y) + bflo(u1.y)) + (bflo(u2.y) + bflo(u3.y));
        a3 += (bfhi(u0.y) + bfhi(u1.y)) + (bfhi(u2.y) + bfhi(u3.y));
    }
    for (; j < e; ++j) {
        uint2 u = *(const uint2*)(S.x + (size_t)S.idx[j] * 256 + 4 * t);
        a0 += bflo(u.x); a1 += bfhi(u.x); a2 += bflo(u.y); a3 += bfhi(u.y);
    }
    S.agg[(size_t)b * 256 + 4 * t]     = f2b(a0);
    S.agg[(size_t)b * 256 + 4 * t + 1] = f2b(a1);
    S.agg[(size_t)b * 256 + 4 * t + 2] = f2b(a2);
    S.agg[(size_t)b * 256 + 4 * t + 3] = f2b(a3);
}

// ---------------- merged dual-side MFMA bf16 GEMM ----------------
// BM=64, BN=256 (full width, no grid.y), BK=32, 256 threads = 4 waves.
struct GSide { const unsigned short* A1; const unsigned short* W1t;
               const unsigned short* A2; const unsigned short* W2t;
               const float* bias; float* outF; unsigned short* outB; int n; };

__global__ __launch_bounds__(256)
void k_mgemm2(GSide s0, GSide s1, int nblk0, int K1, int K2, int act) {
    __shared__ short As[64][40];    // 80B row stride: conflict-benign b128 reads
    __shared__ short Bs[256][40];

    GSide S;
    int bx;
    if ((int)blockIdx.x < nblk0) { S = s0; bx = blockIdx.x; }
    else                          { S = s1; bx = blockIdx.x - nblk0; }

    const int tid = threadIdx.x;
    const int w = tid >> 6, l = tid & 63;
    const int m16 = l & 15, kg = l >> 4;
    const int row0 = bx * 64;

    const f32x4 z4 = {0.f, 0.f, 0.f, 0.f};
    f32x4 acc[4][4];
#pragma unroll
    for (int i = 0; i < 4; ++i)
#pragma unroll
        for (int j = 0; j < 4; ++j) acc[i][j] = z4;

    for (int pass = 0; pass < 2; ++pass) {
        const unsigned short* A  = pass ? S.A2 : S.A1;
        const unsigned short* Wt = pass ? S.W2t : S.W1t;
        const int K = pass ? K2 : K1;
        if (A == nullptr) continue;
        for (int k0 = 0; k0 < K; k0 += 32) {
            {
                const int ar = tid >> 2, ac = (tid & 3) * 8;
                const int gr = row0 + ar;
                short8 v = {0, 0, 0, 0, 0, 0, 0, 0};
                if (gr < S.n) v = *(const short8*)(A + (size_t)gr * K + k0 + ac);
                *(short8*)&As[ar][ac] = v;
#pragma unroll
                for (int h = 0; h < 4; ++h)
                    *(short8*)&Bs[ar + 64 * h][ac] =
                        *(const short8*)(Wt + (size_t)(ar + 64 * h) * K + k0 + ac);
            }
            __syncthreads();
            short8 af[4];
#pragma unroll
            for (int i = 0; i < 4; ++i) af[i] = *(const short8*)&As[16 * i + m16][8 * kg];
#pragma unroll
            for (int j = 0; j < 4; ++j) {
                short8 bf = *(const short8*)&Bs[64 * w + 16 * j + m16][8 * kg];
#pragma unroll
                for (int i = 0; i < 4; ++i)
                    acc[i][j] = __builtin_amdgcn_mfma_f32_16x16x32_bf16(af[i], bf, acc[i][j], 0, 0, 0);
            }
            __syncthreads();
        }
    }

#pragma unroll
    for (int j = 0; j < 4; ++j) {
        const int gc = 64 * w + 16 * j + m16;
        const float bv = S.bias ? S.bias[gc] : 0.f;
#pragma unroll
        for (int i = 0; i < 4; ++i) {
#pragma unroll
            for (int r = 0; r < 4; ++r) {
                const int gr = row0 + 16 * i + 4 * kg + r;
                if (gr < S.n) {
                    float v = acc[i][j][r] + bv;
                    if (act) v = tanhf(v);
                    if (S.outF) S.outF[(size_t)gr * HH + gc] = v;
                    if (S.outB) S.outB[(size_t)gr * HH + gc] = f2b(v);
                }
            }
        }
    }
}

// ---------------- link decoder: one wave per link, bf16 pair-gather ----------------
__global__ void k_decode(const unsigned short* __restrict__ Ab, const unsigned short* __restrict__ Bb,
                         const int* __restrict__ rows, const int* __restrict__ cols,
                         const float* __restrict__ W2, const float* __restrict__ b2,
                         float* __restrict__ out) {
    const int wid = (blockIdx.x * blockDim.x + threadIdx.x) >> 6;
    const int lane = threadIdx.x & 63;
    if (wid >= NL) return;
    const int r = rows[wid], c = cols[wid];
    uint2 ua = *(const uint2*)(Ab + (size_t)r * HH + 4 * lane);
    uint2 ub = *(const uint2*)(Bb + (size_t)c * HH + 4 * lane);
    float4 wv = *(const float4*)(W2 + 4 * lane);
    float s = fmaxf(bflo(ua.x) + bflo(ub.x), 0.f) * wv.x +
              fmaxf(bfhi(ua.x) + bfhi(ub.x), 0.f) * wv.y +
              fmaxf(bflo(ua.y) + bflo(ub.y), 0.f) * wv.z +
              fmaxf(bfhi(ua.y) + bfhi(ub.y), 0.f) * wv.w;
#pragma unroll
    for (int off = 32; off > 0; off >>= 1) s += __shfl_xor(s, off, 64);
    if (lane == 0) out[wid] = s + b2[0];
}

extern "C" void kernel_launch(void* const* d_in, const int* in_sizes, int n_in,
                              void* d_out, int out_size, void* d_ws, size_t ws_size,
                              hipStream_t stream) {
    const float* x_drug  = (const float*)d_in[0];
    const float* x_prot  = (const float*)d_in[1];
    const int*   ei_src  = (const int*)d_in[2];
    const int*   ei_dst  = (const int*)d_in[3];
    const int*   eli_row = (const int*)d_in[4];
    const int*   eli_col = (const int*)d_in[5];
    const float* Wl_in_dp  = (const float*)d_in[6];
    const float* bl_in_dp  = (const float*)d_in[7];
    const float* Wr_in_dp  = (const float*)d_in[8];
    const float* Wl_in_pd  = (const float*)d_in[9];
    const float* bl_in_pd  = (const float*)d_in[10];
    const float* Wr_in_pd  = (const float*)d_in[11];
    const float* Wl_med_dp = (const float*)d_in[12];
    const float* bl_med_dp = (const float*)d_in[13];
    const float* Wr_med_dp = (const float*)d_in[14];
    const float* Wl_med_pd = (const float*)d_in[15];
    const float* bl_med_pd = (const float*)d_in[16];
    const float* Wr_med_pd = (const float*)d_in[17];
    const float* Wl_out_dp = (const float*)d_in[18];
    const float* bl_out_dp = (const float*)d_in[19];
    const float* Wr_out_dp = (const float*)d_in[20];
    const float* Wl_out_pd = (const float*)d_in[21];
    const float* bl_out_pd = (const float*)d_in[22];
    const float* Wr_out_pd = (const float*)d_in[23];
    const float* W1 = (const float*)d_in[24];
    const float* b1 = (const float*)d_in[25];
    const float* W2 = (const float*)d_in[26];
    const float* b2 = (const float*)d_in[27];

    char* ws = (char*)d_ws;
    size_t off = 0;
    auto alloc = [&](size_t bytes) {
        void* p = ws + off;
        off = (off + bytes + 255) & ~(size_t)255;
        return p;
    };

    int* deg_p    = (int*)alloc((size_t)NP * 4);
    int* deg_d    = (int*)alloc((size_t)ND * 4);
    int* rowptr_p = (int*)alloc((size_t)(NP + 1) * 4);
    int* rowptr_d = (int*)alloc((size_t)(ND + 1) * 4);
    int* cur_p    = (int*)alloc((size_t)NP * 4);
    int* cur_d    = (int*)alloc((size_t)ND * 4);
    int* csr_p    = (int*)alloc((size_t)NE * 4);
    int* csr_d    = (int*)alloc((size_t)NE * 4);

    unsigned short* wt[14];
    const int kk[14] = {128,128,128,128, 256,256,256,256, 256,256,256,256, 256,256};
    for (int i = 0; i < 14; ++i) wt[i] = (unsigned short*)alloc((size_t)256 * kk[i] * 2);

    unsigned short* xdbf = (unsigned short*)alloc((size_t)ND * DD * 2);
    unsigned short* xpbf = (unsigned short*)alloc((size_t)NP * DD * 2);
    unsigned short* xd_a = (unsigned short*)alloc((size_t)ND * HH * 2);
    unsigned short* xd_b = (unsigned short*)alloc((size_t)ND * HH * 2);
    unsigned short* xp_a = (unsigned short*)alloc((size_t)NP * HH * 2);
    unsigned short* xp_b = (unsigned short*)alloc((size_t)NP * HH * 2);
    unsigned short* aggd = (unsigned short*)alloc((size_t)ND * HH * 2);
    unsigned short* aggp = (unsigned short*)alloc((size_t)NP * HH * 2);
    unsigned short* zdbf = (unsigned short*)alloc((size_t)ND * HH * 2);
    unsigned short* zpbf = (unsigned short*)alloc((size_t)NP * HH * 2);

    float* zd   = (float*)d_out;
    float* zp   = zd + (size_t)ND * HH;
    float* outv = zp + (size_t)NP * HH;

    const int nbD = (ND + 63) / 64;   // 313
    const int nbP = (NP + 63) / 64;   // 125
    const dim3 gG(nbD + nbP);         // merged GEMM grid (438)
    const dim3 gA((NP + ND + 3) / 4); // merged aggregate grid (7000), 4 nodes/block

    // ---- CSR build ----
    hipMemsetAsync(deg_p, 0, (size_t)NP * 4, stream);
    hipMemsetAsync(deg_d, 0, (size_t)ND * 4, stream);
    k_hist<<<(NE + 255) / 256, 256, 0, stream>>>(ei_src, ei_dst, deg_d, deg_p);
    k_scan2<<<2, 1024, 0, stream>>>(deg_p, rowptr_p, cur_p, NP,
                                    deg_d, rowptr_d, cur_d, ND);
    k_fill<<<(NE + 255) / 256, 256, 0, stream>>>(ei_src, ei_dst, cur_p, cur_d, csr_p, csr_d);

    // ---- input/weight conversion ----
    k_f2b2<<<(ND * DD / 4 + NP * DD / 4 + 255) / 256, 256, 0, stream>>>(
        x_drug, xdbf, ND * DD / 4, x_prot, xpbf, NP * DD / 4);
    {
        WtPack p;
        const float* src[14] = {Wl_in_dp, Wr_in_dp, Wl_in_pd, Wr_in_pd,
                                Wl_med_dp, Wr_med_dp, Wl_med_pd, Wr_med_pd,
                                Wl_out_dp, Wr_out_dp, Wl_out_pd, Wr_out_pd,
                                W1, W1 + (size_t)HH * HH};
        for (int i = 0; i < 14; ++i) {
            p.d[i].src = src[i];
            p.d[i].dst = wt[i];
            p.d[i].kbits = (kk[i] == 128) ? 7 : 8;
        }
        k_wt<<<dim3(256, 14), 256, 0, stream>>>(p);
    }

    // side structs: P-aggregate gathers drug rows for proteins; D-aggregate the reverse
    ASide aP128 = {xdbf, rowptr_p, csr_p, aggp, NP};
    ASide aD128 = {xpbf, rowptr_d, csr_d, aggd, ND};

    // ---- layer in (K=128), tanh -> xp_a/xd_a ----
    k_agg2_128<<<gA, 256, 0, stream>>>(aP128, aD128);
    {
        GSide d = {aggd, wt[2], xdbf, wt[3], bl_in_pd, nullptr, xd_a, ND};
        GSide pS = {aggp, wt[0], xpbf, wt[1], bl_in_dp, nullptr, xp_a, NP};
        k_mgemm2<<<gG, 256, 0, stream>>>(d, pS, nbD, 128, 128, 1);
    }

    // ---- med layer 1 -> xp_b/xd_b ----
    {
        ASide aP = {xd_a, rowptr_p, csr_p, aggp, NP};
        ASide aD = {xp_a, rowptr_d, csr_d, aggd, ND};
        k_agg2_256<<<gA, 256, 0, stream>>>(aP, aD);
        GSide d = {aggd, wt[6], xd_a, wt[7], bl_med_pd, nullptr, xd_b, ND};
        GSide pS = {aggp, wt[4], xp_a, wt[5], bl_med_dp, nullptr, xp_b, NP};
        k_mgemm2<<<gG, 256, 0, stream>>>(d, pS, nbD, 256, 256, 1);
    }

    // ---- med layer 2 -> xp_a/xd_a ----
    {
        ASide aP = {xd_b, rowptr_p, csr_p, aggp, NP};
        ASide aD = {xp_b, rowptr_d, csr_d, aggd, ND};
        k_agg2_256<<<gA, 256, 0, stream>>>(aP, aD);
        GSide d = {aggd, wt[6], xd_b, wt[7], bl_med_pd, nullptr, xd_a, ND};
        GSide pS = {aggp, wt[4], xp_b, wt[5], bl_med_dp, nullptr, xp_a, NP};
        k_mgemm2<<<gG, 256, 0, stream>>>(d, pS, nbD, 256, 256, 1);
    }

    // ---- layer out (no act): f32 -> d_out, bf16 -> zdbf/zpbf ----
    {
        ASide aP = {xd_a, rowptr_p, csr_p, aggp, NP};
        ASide aD = {xp_a, rowptr_d, csr_d, aggd, ND};
        k_agg2_256<<<gA, 256, 0, stream>>>(aP, aD);
        GSide d = {aggd, wt[10], xd_a, wt[11], bl_out_pd, zd, zdbf, ND};
        GSide pS = {aggp, wt[8], xp_a, wt[9], bl_out_dp, zp, zpbf, NP};
        k_mgemm2<<<gG, 256, 0, stream>>>(d, pS, nbD, 256, 256, 0);
    }

    // ---- decoder: A = zd@W1_top -> xd_b, B = zp@W1_bot + b1 -> xp_b (relu in k_decode) ----
    {
        GSide d = {zdbf, wt[12], nullptr, nullptr, nullptr, nullptr, xd_b, ND};
        GSide pS = {zpbf, wt[13], nullptr, nullptr, b1, nullptr, xp_b, NP};
        k_mgemm2<<<gG, 256, 0, stream>>>(d, pS, nbD, 256, 256, 0);
    }
    k_decode<<<(NL + 3) / 4, 256, 0, stream>>>(xd_b, xp_b, eli_row, eli_col, W2, b2, outv);
}